// Round 1
// baseline (641.655 us; speedup 1.0000x reference)
//
#include <hip/hip_runtime.h>
#include <hip/hip_bf16.h>
#include <math.h>

// Problem constants
#define V_SRC 32000
#define V_DST 32000
#define EDIM  512
#define HDIM  512
#define BB    64
#define SS    2048
#define G3H   1536   // 3*HDIM

// ---------------------------------------------------------------------------
// K1: x = relu(emb[idx[b]])          grid: 64 blocks x 128 thr (float4 each)
// ---------------------------------------------------------------------------
__global__ __launch_bounds__(128) void k_embed(const int* __restrict__ idx,
                                               const float* __restrict__ emb,
                                               float* __restrict__ x) {
    int b = blockIdx.x;
    int t = threadIdx.x;           // 0..127, 128*4 = 512 floats
    int row = idx[b];
    float4 v = *(const float4*)(emb + (size_t)row * EDIM + t * 4);
    v.x = fmaxf(v.x, 0.f); v.y = fmaxf(v.y, 0.f);
    v.z = fmaxf(v.z, 0.f); v.w = fmaxf(v.w, 0.f);
    *(float4*)(x + (size_t)b * EDIM + t * 4) = v;
}

// ---------------------------------------------------------------------------
// K2: gi[b,j] = x[b,:].W_ih[j,:]   gh[b,j] = h0[b,:].W_hh[j,:]
// One wave per j row (coalesced W reads, lane holds 8 W elems), loop over b.
// grid: 384 blocks x 256 thr (4 waves)
// ---------------------------------------------------------------------------
__global__ __launch_bounds__(256) void k_gru_gemv(const float* __restrict__ x,
                                                  const float* __restrict__ h0,
                                                  const float* __restrict__ W_ih,
                                                  const float* __restrict__ W_hh,
                                                  float* __restrict__ gi,
                                                  float* __restrict__ gh) {
    int w    = threadIdx.x >> 6;
    int lane = threadIdx.x & 63;
    int j    = blockIdx.x * 4 + w;          // 0..1535

    float4 wi1 = *(const float4*)(W_ih + (size_t)j * EDIM + lane * 4);
    float4 wi2 = *(const float4*)(W_ih + (size_t)j * EDIM + 256 + lane * 4);
    float4 wh1 = *(const float4*)(W_hh + (size_t)j * HDIM + lane * 4);
    float4 wh2 = *(const float4*)(W_hh + (size_t)j * HDIM + 256 + lane * 4);

    for (int b = 0; b < BB; b++) {
        float4 x1 = *(const float4*)(x  + (size_t)b * EDIM + lane * 4);
        float4 x2 = *(const float4*)(x  + (size_t)b * EDIM + 256 + lane * 4);
        float4 h1 = *(const float4*)(h0 + (size_t)b * HDIM + lane * 4);
        float4 h2 = *(const float4*)(h0 + (size_t)b * HDIM + 256 + lane * 4);
        float pi = x1.x*wi1.x + x1.y*wi1.y + x1.z*wi1.z + x1.w*wi1.w
                 + x2.x*wi2.x + x2.y*wi2.y + x2.z*wi2.z + x2.w*wi2.w;
        float ph = h1.x*wh1.x + h1.y*wh1.y + h1.z*wh1.z + h1.w*wh1.w
                 + h2.x*wh2.x + h2.y*wh2.y + h2.z*wh2.z + h2.w*wh2.w;
        #pragma unroll
        for (int off = 32; off; off >>= 1) {
            pi += __shfl_xor(pi, off);
            ph += __shfl_xor(ph, off);
        }
        if (lane == 0) {
            gi[(size_t)b * G3H + j] = pi;
            gh[(size_t)b * G3H + j] = ph;
        }
    }
}

// ---------------------------------------------------------------------------
// K3: GRU gates -> h ; h goes to concat[b][0:512] and d_out dec_hidden slot
// grid: 64 x 128 thr (float4 each)
// ---------------------------------------------------------------------------
__device__ __forceinline__ float sigmoidf_(float v) {
    return 1.f / (1.f + __expf(-v));
}

__global__ __launch_bounds__(128) void k_gru_gates(const float* __restrict__ gi,
                                                   const float* __restrict__ gh,
                                                   const float* __restrict__ h0,
                                                   const float* __restrict__ b_ih,
                                                   const float* __restrict__ b_hh,
                                                   float* __restrict__ concat,
                                                   float* __restrict__ hout) {
    int b = blockIdx.x;
    int i = threadIdx.x * 4;      // 0..508
    const float* gib = gi + (size_t)b * G3H;
    const float* ghb = gh + (size_t)b * G3H;

    float4 gir = *(const float4*)(gib + i);
    float4 giz = *(const float4*)(gib + i + 512);
    float4 gin = *(const float4*)(gib + i + 1024);
    float4 ghr = *(const float4*)(ghb + i);
    float4 ghz = *(const float4*)(ghb + i + 512);
    float4 ghn = *(const float4*)(ghb + i + 1024);
    float4 bir = *(const float4*)(b_ih + i);
    float4 biz = *(const float4*)(b_ih + i + 512);
    float4 bin = *(const float4*)(b_ih + i + 1024);
    float4 bhr = *(const float4*)(b_hh + i);
    float4 bhz = *(const float4*)(b_hh + i + 512);
    float4 bhn = *(const float4*)(b_hh + i + 1024);
    float4 hv  = *(const float4*)(h0 + (size_t)b * HDIM + i);

    float4 o;
    {
        float r = sigmoidf_(gir.x + bir.x + ghr.x + bhr.x);
        float z = sigmoidf_(giz.x + biz.x + ghz.x + bhz.x);
        float n = tanhf(gin.x + bin.x + r * (ghn.x + bhn.x));
        o.x = (1.f - z) * n + z * hv.x;
    }
    {
        float r = sigmoidf_(gir.y + bir.y + ghr.y + bhr.y);
        float z = sigmoidf_(giz.y + biz.y + ghz.y + bhz.y);
        float n = tanhf(gin.y + bin.y + r * (ghn.y + bhn.y));
        o.y = (1.f - z) * n + z * hv.y;
    }
    {
        float r = sigmoidf_(gir.z + bir.z + ghr.z + bhr.z);
        float z = sigmoidf_(giz.z + biz.z + ghz.z + bhz.z);
        float n = tanhf(gin.z + bin.z + r * (ghn.z + bhn.z));
        o.z = (1.f - z) * n + z * hv.z;
    }
    {
        float r = sigmoidf_(gir.w + bir.w + ghr.w + bhr.w);
        float z = sigmoidf_(giz.w + biz.w + ghz.w + bhz.w);
        float n = tanhf(gin.w + bin.w + r * (ghn.w + bhn.w));
        o.w = (1.f - z) * n + z * hv.w;
    }
    *(float4*)(concat + (size_t)b * 1024 + i) = o;
    *(float4*)(hout   + (size_t)b * HDIM + i) = o;
}

// ---------------------------------------------------------------------------
// K4: u[b,j] = sum_i h[b,i] * W_attn[i,j]   (u = h @ W_attn)
// NOTE: b_attn is deliberately dropped: alpha[b,s] = enc.u + const(b), and a
// per-row constant cancels in softmax.
// grid: 64 x 256 thr (each thread handles j and j+256)
// ---------------------------------------------------------------------------
__global__ __launch_bounds__(256) void k_attn_u(const float* __restrict__ concat,
                                                const float* __restrict__ W_attn,
                                                float* __restrict__ u) {
    int b = blockIdx.x;
    int j = threadIdx.x;
    const float* hrow = concat + (size_t)b * 1024;   // h half
    float a0 = 0.f, a1 = 0.f;
    for (int i = 0; i < HDIM; i++) {
        float hvv = hrow[i];                         // uniform across threads
        a0 = fmaf(hvv, W_attn[(size_t)i * HDIM + j],       a0);
        a1 = fmaf(hvv, W_attn[(size_t)i * HDIM + j + 256], a1);
    }
    u[(size_t)b * HDIM + j]       = a0;
    u[(size_t)b * HDIM + j + 256] = a1;
}

// ---------------------------------------------------------------------------
// K5: flash-style single pass over enc_outputs.
// grid: (32 tiles, 64 b), 256 thr = 4 waves. Each wave: 16 s-rows, full
// 512-wide acc (8 floats/lane), online softmax (m,l). Block merges 4 waves'
// partials -> (pm,pl,pacc)[b][tile].
// ---------------------------------------------------------------------------
__global__ __launch_bounds__(256) void k_attn_flash(const float* __restrict__ enc,
                                                    const float* __restrict__ u,
                                                    float* __restrict__ pm,
                                                    float* __restrict__ pl,
                                                    float* __restrict__ pacc) {
    int tile = blockIdx.x;         // 0..31
    int b    = blockIdx.y;         // 0..63
    int w    = threadIdx.x >> 6;
    int lane = threadIdx.x & 63;

    float4 u1 = *(const float4*)(u + (size_t)b * HDIM + lane * 4);
    float4 u2 = *(const float4*)(u + (size_t)b * HDIM + 256 + lane * 4);

    float m = -INFINITY, l = 0.f;
    float4 a1 = {0.f, 0.f, 0.f, 0.f};
    float4 a2 = {0.f, 0.f, 0.f, 0.f};

    for (int it = 0; it < 16; it++) {
        int s = tile * 64 + it * 4 + w;
        const float* row = enc + ((size_t)s * BB + b) * HDIM;
        float4 e1 = *(const float4*)(row + lane * 4);
        float4 e2 = *(const float4*)(row + 256 + lane * 4);
        float p = e1.x*u1.x + e1.y*u1.y + e1.z*u1.z + e1.w*u1.w
                + e2.x*u2.x + e2.y*u2.y + e2.z*u2.z + e2.w*u2.w;
        #pragma unroll
        for (int off = 32; off; off >>= 1) p += __shfl_xor(p, off);

        float wt;
        if (p > m) {                       // wave-uniform branch
            float sc = __expf(m - p);      // first iter: exp(-inf)=0
            l *= sc;
            a1.x *= sc; a1.y *= sc; a1.z *= sc; a1.w *= sc;
            a2.x *= sc; a2.y *= sc; a2.z *= sc; a2.w *= sc;
            m = p;
            wt = 1.f;
        } else {
            wt = __expf(p - m);
        }
        l += wt;
        a1.x = fmaf(wt, e1.x, a1.x); a1.y = fmaf(wt, e1.y, a1.y);
        a1.z = fmaf(wt, e1.z, a1.z); a1.w = fmaf(wt, e1.w, a1.w);
        a2.x = fmaf(wt, e2.x, a2.x); a2.y = fmaf(wt, e2.y, a2.y);
        a2.z = fmaf(wt, e2.z, a2.z); a2.w = fmaf(wt, e2.w, a2.w);
    }

    // merge 4 waves
    __shared__ float sm[4], sl[4];
    __shared__ float sacc[4][512];
    if (lane == 0) { sm[w] = m; sl[w] = l; }
    *(float4*)&sacc[w][lane * 4]       = a1;
    *(float4*)&sacc[w][256 + lane * 4] = a2;
    __syncthreads();

    float M  = fmaxf(fmaxf(sm[0], sm[1]), fmaxf(sm[2], sm[3]));
    float s0 = __expf(sm[0] - M), s1 = __expf(sm[1] - M);
    float s2 = __expf(sm[2] - M), s3 = __expf(sm[3] - M);
    float L  = s0 * sl[0] + s1 * sl[1] + s2 * sl[2] + s3 * sl[3];

    int tid  = threadIdx.x;
    int pidx = b * 32 + tile;
    float acc0 = s0 * sacc[0][tid] + s1 * sacc[1][tid]
               + s2 * sacc[2][tid] + s3 * sacc[3][tid];
    float acc1 = s0 * sacc[0][tid + 256] + s1 * sacc[1][tid + 256]
               + s2 * sacc[2][tid + 256] + s3 * sacc[3][tid + 256];
    if (tid == 0) { pm[pidx] = M; pl[pidx] = L; }
    pacc[(size_t)pidx * HDIM + tid]       = acc0;
    pacc[(size_t)pidx * HDIM + tid + 256] = acc1;
}

// ---------------------------------------------------------------------------
// K6: combine 32 tile-partials per b -> context -> concat[b][512:1024]
// grid: 64 x 256 thr
// ---------------------------------------------------------------------------
__global__ __launch_bounds__(256) void k_attn_combine(const float* __restrict__ pm,
                                                      const float* __restrict__ pl,
                                                      const float* __restrict__ pacc,
                                                      float* __restrict__ concat) {
    int b   = blockIdx.x;
    int tid = threadIdx.x;
    __shared__ float smv[32], spl[32], ssc[32];
    if (tid < 32) {
        smv[tid] = pm[b * 32 + tid];
        spl[tid] = pl[b * 32 + tid];
    }
    __syncthreads();
    float M = smv[0];
    #pragma unroll
    for (int t = 1; t < 32; t++) M = fmaxf(M, smv[t]);
    if (tid < 32) ssc[tid] = __expf(smv[tid] - M);
    __syncthreads();

    float L = 0.f;
    #pragma unroll
    for (int t = 0; t < 32; t++) L += ssc[t] * spl[t];

    float c0 = 0.f, c1 = 0.f;
    for (int t = 0; t < 32; t++) {
        const float* pa = pacc + (size_t)(b * 32 + t) * HDIM;
        c0 = fmaf(ssc[t], pa[tid],       c0);
        c1 = fmaf(ssc[t], pa[tid + 256], c1);
    }
    float inv = 1.f / L;
    concat[(size_t)b * 1024 + 512 + tid]       = c0 * inv;
    concat[(size_t)b * 1024 + 512 + tid + 256] = c1 * inv;
}

// ---------------------------------------------------------------------------
// K7: logits[b,v] = concat[b,:].W_cls[v,:] + b_cls[v]  -> written into d_out
// Tiled f32 GEMM: block = 64b x 64v tile, 256 thr (thread = 4b x 4v),
// k-chunks of 64 staged in LDS. W tile XOR-swizzled (16B-aligned strides
// alone would force 8-way bank conflicts on the v-major reads).
// grid: 500 x 256 thr
// ---------------------------------------------------------------------------
#define LDSTR 68   // padded row stride (floats); 68*4=272B = 17*16 (b128-aligned)

__global__ __launch_bounds__(256) void k_classifier(const float* __restrict__ concat,
                                                    const float* __restrict__ W_cls,
                                                    const float* __restrict__ b_cls,
                                                    float* __restrict__ logits) {
    __shared__ float A_lds[64 * LDSTR];
    __shared__ float W_lds[64 * LDSTR];
    int t  = threadIdx.x;
    int tx = t & 15;          // -> v
    int ty = t >> 4;          // -> b
    int vbase = blockIdx.x * 64;
    int swz = (tx & 7) << 2;  // row-group XOR swizzle for W reads

    float acc[4][4] = {};

    for (int kc = 0; kc < 16; kc++) {
        int k0 = kc * 64;
        #pragma unroll
        for (int j = 0; j < 4; j++) {
            int idx = t + j * 256;
            int row = idx >> 4;            // 0..63
            int col = (idx & 15) * 4;      // 0..60
            float4 av = *(const float4*)(concat + (size_t)row * 1024 + k0 + col);
            *(float4*)&A_lds[row * LDSTR + col] = av;
            float4 wv = *(const float4*)(W_cls + (size_t)(vbase + row) * 1024 + k0 + col);
            int csw = col ^ (((row >> 2) & 7) << 2);
            *(float4*)&W_lds[row * LDSTR + csw] = wv;
        }
        __syncthreads();

        #pragma unroll
        for (int ks = 0; ks < 16; ks++) {
            int kk = ks * 4;
            int kw = kk ^ swz;
            float4 a0 = *(float4*)&A_lds[(ty * 4 + 0) * LDSTR + kk];
            float4 a1 = *(float4*)&A_lds[(ty * 4 + 1) * LDSTR + kk];
            float4 a2 = *(float4*)&A_lds[(ty * 4 + 2) * LDSTR + kk];
            float4 a3 = *(float4*)&A_lds[(ty * 4 + 3) * LDSTR + kk];
            float4 w0 = *(float4*)&W_lds[(tx * 4 + 0) * LDSTR + kw];
            float4 w1 = *(float4*)&W_lds[(tx * 4 + 1) * LDSTR + kw];
            float4 w2 = *(float4*)&W_lds[(tx * 4 + 2) * LDSTR + kw];
            float4 w3 = *(float4*)&W_lds[(tx * 4 + 3) * LDSTR + kw];
            float4 aa[4] = {a0, a1, a2, a3};
            float4 ww[4] = {w0, w1, w2, w3};
            #pragma unroll
            for (int i = 0; i < 4; i++)
                #pragma unroll
                for (int jj = 0; jj < 4; jj++) {
                    acc[i][jj] = fmaf(aa[i].x, ww[jj].x, acc[i][jj]);
                    acc[i][jj] = fmaf(aa[i].y, ww[jj].y, acc[i][jj]);
                    acc[i][jj] = fmaf(aa[i].z, ww[jj].z, acc[i][jj]);
                    acc[i][jj] = fmaf(aa[i].w, ww[jj].w, acc[i][jj]);
                }
        }
        __syncthreads();
    }

    float4 bc = *(const float4*)(b_cls + vbase + tx * 4);
    #pragma unroll
    for (int i = 0; i < 4; i++) {
        float4 o;
        o.x = acc[i][0] + bc.x;
        o.y = acc[i][1] + bc.y;
        o.z = acc[i][2] + bc.z;
        o.w = acc[i][3] + bc.w;
        *(float4*)&logits[(size_t)(ty * 4 + i) * V_DST + vbase + tx * 4] = o;
    }
}

// ---------------------------------------------------------------------------
// K8: in-place log_softmax over each row of logits (= d_out out region).
// grid: 64 x 256 thr. 3 passes (max, sumexp, subtract); row is L2-hot.
// ---------------------------------------------------------------------------
__global__ __launch_bounds__(256) void k_logsoftmax(float* __restrict__ logits) {
    int b    = blockIdx.x;
    int tid  = threadIdx.x;
    int w    = tid >> 6, lane = tid & 63;
    float4* row = (float4*)(logits + (size_t)b * V_DST);   // 8000 float4
    __shared__ float sm4[4], sl4[4];

    float m = -INFINITY;
    for (int i = tid; i < 8000; i += 256) {
        float4 v = row[i];
        m = fmaxf(m, fmaxf(fmaxf(v.x, v.y), fmaxf(v.z, v.w)));
    }
    #pragma unroll
    for (int off = 32; off; off >>= 1) m = fmaxf(m, __shfl_xor(m, off));
    if (lane == 0) sm4[w] = m;
    __syncthreads();
    float M = fmaxf(fmaxf(sm4[0], sm4[1]), fmaxf(sm4[2], sm4[3]));

    float l = 0.f;
    for (int i = tid; i < 8000; i += 256) {
        float4 v = row[i];
        l += __expf(v.x - M) + __expf(v.y - M) + __expf(v.z - M) + __expf(v.w - M);
    }
    #pragma unroll
    for (int off = 32; off; off >>= 1) l += __shfl_xor(l, off);
    if (lane == 0) sl4[w] = l;
    __syncthreads();
    float L   = sl4[0] + sl4[1] + sl4[2] + sl4[3];
    float lse = M + logf(L);

    for (int i = tid; i < 8000; i += 256) {
        float4 v = row[i];
        v.x -= lse; v.y -= lse; v.z -= lse; v.w -= lse;
        row[i] = v;
    }
}

// ---------------------------------------------------------------------------
// launch
// ---------------------------------------------------------------------------
extern "C" void kernel_launch(void* const* d_in, const int* in_sizes, int n_in,
                              void* d_out, int out_size, void* d_ws, size_t ws_size,
                              hipStream_t stream) {
    const int*   dec_inputs = (const int*)  d_in[0];
    const float* enc        = (const float*)d_in[1];
    const float* h0         = (const float*)d_in[2];   // [1,B,H] == [B,H]
    const float* emb        = (const float*)d_in[3];
    const float* W_ih       = (const float*)d_in[4];
    const float* W_hh       = (const float*)d_in[5];
    const float* b_ih       = (const float*)d_in[6];
    const float* b_hh       = (const float*)d_in[7];
    const float* W_attn     = (const float*)d_in[8];
    // d_in[9] = b_attn: unused — constant-per-row shift cancels in softmax
    const float* W_cls      = (const float*)d_in[10];
    const float* b_cls      = (const float*)d_in[11];

    float* out  = (float*)d_out;            // [64][32000] log-probs
    float* hout = out + (size_t)BB * V_DST; // [64][512] dec_hidden

    // workspace layout (floats)
    float* ws     = (float*)d_ws;
    float* x      = ws;                 //  64*512            = 32768
    float* gi     = ws + 32768;         //  64*1536           = 98304
    float* gh     = ws + 131072;        //  64*1536
    float* concat = ws + 229376;        //  64*1024  (h | context)
    float* u      = ws + 294912;        //  64*512
    float* pm     = ws + 327680;        //  64*32
    float* pl     = ws + 329728;        //  64*32
    float* pacc   = ws + 331776;        //  64*32*512 = 1048576  (ends 1380352 floats = 5.5 MB)

    k_embed      <<<64,          128, 0, stream>>>(dec_inputs, emb, x);
    k_gru_gemv   <<<384,         256, 0, stream>>>(x, h0, W_ih, W_hh, gi, gh);
    k_gru_gates  <<<64,          128, 0, stream>>>(gi, gh, h0, b_ih, b_hh, concat, hout);
    k_attn_u     <<<64,          256, 0, stream>>>(concat, W_attn, u);
    k_attn_flash <<<dim3(32,64), 256, 0, stream>>>(enc, u, pm, pl, pacc);
    k_attn_combine<<<64,         256, 0, stream>>>(pm, pl, pacc, concat);
    k_classifier <<<500,         256, 0, stream>>>(concat, W_cls, b_cls, out);
    k_logsoftmax <<<64,          256, 0, stream>>>(out);
}

// Round 8
// 628.896 us; speedup vs baseline: 1.0203x; 1.0203x over previous
//
#include <hip/hip_runtime.h>
#include <hip/hip_bf16.h>
#include <math.h>

// Problem constants
#define V_SRC 32000
#define V_DST 32000
#define EDIM  512
#define HDIM  512
#define BB    64
#define SS    2048
#define G3H   1536   // 3*HDIM

typedef __attribute__((ext_vector_type(8))) short bfrag8;   // 8 bf16 (4 VGPRs)
typedef __attribute__((ext_vector_type(4))) float f4v;      // MFMA acc

// split f32 -> (hi, lo) bf16 pair: hi = truncate upper16, lo = RNE(residual).
// hi+lo carries ~16 mantissa bits => ~f32-quality dot products.
__device__ __forceinline__ void split_bf16(float x, unsigned short& h, unsigned short& l) {
    unsigned u  = __float_as_uint(x);
    unsigned hb = u & 0xFFFF0000u;
    h = (unsigned short)(u >> 16);
    float r = x - __uint_as_float(hb);
    unsigned v = __float_as_uint(r);
    v += 0x7FFFu + ((v >> 16) & 1u);
    l = (unsigned short)(v >> 16);
}

__device__ __forceinline__ float sigmoidf_(float v) {
    return 1.f / (1.f + __expf(-v));
}

// ---------------------------------------------------------------------------
// K1: fused embed+relu + GRU input/hidden GEMV.
// gi[b,j] = relu(emb[idx[b]]).W_ih[j,:]   gh[b,j] = h0[b,:].W_hh[j,:]
// wave per j row (W rows held in regs), loop over b. grid: 384 x 256
// ---------------------------------------------------------------------------
__global__ __launch_bounds__(256) void k_gru_gemv(const int* __restrict__ idx,
                                                  const float* __restrict__ emb,
                                                  const float* __restrict__ h0,
                                                  const float* __restrict__ W_ih,
                                                  const float* __restrict__ W_hh,
                                                  float* __restrict__ gi,
                                                  float* __restrict__ gh) {
    int w    = threadIdx.x >> 6;
    int lane = threadIdx.x & 63;
    int j    = blockIdx.x * 4 + w;          // 0..1535

    float4 wi1 = *(const float4*)(W_ih + (size_t)j * EDIM + lane * 4);
    float4 wi2 = *(const float4*)(W_ih + (size_t)j * EDIM + 256 + lane * 4);
    float4 wh1 = *(const float4*)(W_hh + (size_t)j * HDIM + lane * 4);
    float4 wh2 = *(const float4*)(W_hh + (size_t)j * HDIM + 256 + lane * 4);

    for (int b = 0; b < BB; b++) {
        int row = idx[b];
        const float* er = emb + (size_t)row * EDIM;
        float4 x1 = *(const float4*)(er + lane * 4);
        float4 x2 = *(const float4*)(er + 256 + lane * 4);
        x1.x = fmaxf(x1.x, 0.f); x1.y = fmaxf(x1.y, 0.f);
        x1.z = fmaxf(x1.z, 0.f); x1.w = fmaxf(x1.w, 0.f);
        x2.x = fmaxf(x2.x, 0.f); x2.y = fmaxf(x2.y, 0.f);
        x2.z = fmaxf(x2.z, 0.f); x2.w = fmaxf(x2.w, 0.f);
        float4 h1 = *(const float4*)(h0 + (size_t)b * HDIM + lane * 4);
        float4 h2 = *(const float4*)(h0 + (size_t)b * HDIM + 256 + lane * 4);
        float pi = x1.x*wi1.x + x1.y*wi1.y + x1.z*wi1.z + x1.w*wi1.w
                 + x2.x*wi2.x + x2.y*wi2.y + x2.z*wi2.z + x2.w*wi2.w;
        float ph = h1.x*wh1.x + h1.y*wh1.y + h1.z*wh1.z + h1.w*wh1.w
                 + h2.x*wh2.x + h2.y*wh2.y + h2.z*wh2.z + h2.w*wh2.w;
        #pragma unroll
        for (int off = 32; off; off >>= 1) {
            pi += __shfl_xor(pi, off);
            ph += __shfl_xor(ph, off);
        }
        if (lane == 0) {
            gi[(size_t)b * G3H + j] = pi;
            gh[(size_t)b * G3H + j] = ph;
        }
    }
}

// ---------------------------------------------------------------------------
// K2: GRU gates -> h. Emits: h (f32, ws), hout (d_out), concatH/L[0:512] bf16.
// grid: 64 x 128
// ---------------------------------------------------------------------------
__global__ __launch_bounds__(128) void k_gru_gates(const float* __restrict__ gi,
                                                   const float* __restrict__ gh,
                                                   const float* __restrict__ h0,
                                                   const float* __restrict__ b_ih,
                                                   const float* __restrict__ b_hh,
                                                   float* __restrict__ h,
                                                   float* __restrict__ hout,
                                                   unsigned short* __restrict__ cH,
                                                   unsigned short* __restrict__ cL) {
    int b = blockIdx.x;
    int i = threadIdx.x * 4;      // 0..508
    const float* gib = gi + (size_t)b * G3H;
    const float* ghb = gh + (size_t)b * G3H;

    float4 gir = *(const float4*)(gib + i);
    float4 giz = *(const float4*)(gib + i + 512);
    float4 gin = *(const float4*)(gib + i + 1024);
    float4 ghr = *(const float4*)(ghb + i);
    float4 ghz = *(const float4*)(ghb + i + 512);
    float4 ghn = *(const float4*)(ghb + i + 1024);
    float4 bir = *(const float4*)(b_ih + i);
    float4 biz = *(const float4*)(b_ih + i + 512);
    float4 bin = *(const float4*)(b_ih + i + 1024);
    float4 bhr = *(const float4*)(b_hh + i);
    float4 bhz = *(const float4*)(b_hh + i + 512);
    float4 bhn = *(const float4*)(b_hh + i + 1024);
    float4 hv  = *(const float4*)(h0 + (size_t)b * HDIM + i);

    float o[4], hvv[4] = {hv.x, hv.y, hv.z, hv.w};
    float girv[4] = {gir.x, gir.y, gir.z, gir.w}, gizv[4] = {giz.x, giz.y, giz.z, giz.w};
    float ginv[4] = {gin.x, gin.y, gin.z, gin.w}, ghrv[4] = {ghr.x, ghr.y, ghr.z, ghr.w};
    float ghzv[4] = {ghz.x, ghz.y, ghz.z, ghz.w}, ghnv[4] = {ghn.x, ghn.y, ghn.z, ghn.w};
    float birv[4] = {bir.x, bir.y, bir.z, bir.w}, bizv[4] = {biz.x, biz.y, biz.z, biz.w};
    float binv[4] = {bin.x, bin.y, bin.z, bin.w}, bhrv[4] = {bhr.x, bhr.y, bhr.z, bhr.w};
    float bhzv[4] = {bhz.x, bhz.y, bhz.z, bhz.w}, bhnv[4] = {bhn.x, bhn.y, bhn.z, bhn.w};

    unsigned short hs[4], ls[4];
    #pragma unroll
    for (int q = 0; q < 4; q++) {
        float r = sigmoidf_(girv[q] + birv[q] + ghrv[q] + bhrv[q]);
        float z = sigmoidf_(gizv[q] + bizv[q] + ghzv[q] + bhzv[q]);
        float n = tanhf(ginv[q] + binv[q] + r * (ghnv[q] + bhnv[q]));
        o[q] = (1.f - z) * n + z * hvv[q];
        split_bf16(o[q], hs[q], ls[q]);
    }
    float4 of = {o[0], o[1], o[2], o[3]};
    *(float4*)(h    + (size_t)b * HDIM + i) = of;
    *(float4*)(hout + (size_t)b * HDIM + i) = of;
    ushort4 hh = {hs[0], hs[1], hs[2], hs[3]};
    ushort4 ll = {ls[0], ls[1], ls[2], ls[3]};
    *(ushort4*)(cH + (size_t)b * 1024 + i) = hh;
    *(ushort4*)(cL + (size_t)b * 1024 + i) = ll;
}

// ---------------------------------------------------------------------------
// K3: split-K u projection: u_part[kc][b][j] = sum_{i in kc-chunk} h[b,i]W[i,j]
// b_attn dropped (constant per softmax row). grid: dim3(8,64) x 256
// ---------------------------------------------------------------------------
__global__ __launch_bounds__(256) void k_u(const float* __restrict__ h,
                                           const float* __restrict__ W_attn,
                                           float* __restrict__ u_part) {
    int kc = blockIdx.x;     // 0..7
    int b  = blockIdx.y;     // 0..63
    int t  = threadIdx.x;    // 0..255
    __shared__ float hl[64];
    if (t < 64) hl[t] = h[(size_t)b * HDIM + kc * 64 + t];
    __syncthreads();
    const float* Wp = W_attn + (size_t)(kc * 64) * HDIM;
    float a0 = 0.f, a1 = 0.f;
    #pragma unroll 8
    for (int i = 0; i < 64; i++) {
        float hv = hl[i];
        a0 = fmaf(hv, Wp[(size_t)i * HDIM + t],       a0);
        a1 = fmaf(hv, Wp[(size_t)i * HDIM + t + 256], a1);
    }
    u_part[(size_t)(kc * 64 + b) * HDIM + t]       = a0;
    u_part[(size_t)(kc * 64 + b) * HDIM + t + 256] = a1;
}

// ---------------------------------------------------------------------------
// K4: flash-style single pass over enc_outputs (sums u_part in prologue).
// grid: dim3(32,64) x 256 (4 waves; wave = 16 s-rows; online softmax)
// ---------------------------------------------------------------------------
__global__ __launch_bounds__(256) void k_attn_flash(const float* __restrict__ enc,
                                                    const float* __restrict__ u_part,
                                                    float* __restrict__ pm,
                                                    float* __restrict__ pl,
                                                    float* __restrict__ pacc) {
    int tile = blockIdx.x;         // 0..31
    int b    = blockIdx.y;         // 0..63
    int w    = threadIdx.x >> 6;
    int lane = threadIdx.x & 63;

    float4 u1 = {0.f,0.f,0.f,0.f}, u2 = {0.f,0.f,0.f,0.f};
    #pragma unroll
    for (int kc = 0; kc < 8; kc++) {
        const float* up = u_part + (size_t)(kc * 64 + b) * HDIM;
        float4 p1 = *(const float4*)(up + lane * 4);
        float4 p2 = *(const float4*)(up + 256 + lane * 4);
        u1.x += p1.x; u1.y += p1.y; u1.z += p1.z; u1.w += p1.w;
        u2.x += p2.x; u2.y += p2.y; u2.z += p2.z; u2.w += p2.w;
    }

    float m = -INFINITY, l = 0.f;
    float4 a1 = {0.f, 0.f, 0.f, 0.f};
    float4 a2 = {0.f, 0.f, 0.f, 0.f};

    for (int it = 0; it < 16; it++) {
        int s = tile * 64 + it * 4 + w;
        const float* row = enc + ((size_t)s * BB + b) * HDIM;
        float4 e1 = *(const float4*)(row + lane * 4);
        float4 e2 = *(const float4*)(row + 256 + lane * 4);
        float p = e1.x*u1.x + e1.y*u1.y + e1.z*u1.z + e1.w*u1.w
                + e2.x*u2.x + e2.y*u2.y + e2.z*u2.z + e2.w*u2.w;
        #pragma unroll
        for (int off = 32; off; off >>= 1) p += __shfl_xor(p, off);

        float wt;
        if (p > m) {                       // wave-uniform branch
            float sc = __expf(m - p);      // first iter: exp(-inf)=0
            l *= sc;
            a1.x *= sc; a1.y *= sc; a1.z *= sc; a1.w *= sc;
            a2.x *= sc; a2.y *= sc; a2.z *= sc; a2.w *= sc;
            m = p;
            wt = 1.f;
        } else {
            wt = __expf(p - m);
        }
        l += wt;
        a1.x = fmaf(wt, e1.x, a1.x); a1.y = fmaf(wt, e1.y, a1.y);
        a1.z = fmaf(wt, e1.z, a1.z); a1.w = fmaf(wt, e1.w, a1.w);
        a2.x = fmaf(wt, e2.x, a2.x); a2.y = fmaf(wt, e2.y, a2.y);
        a2.z = fmaf(wt, e2.z, a2.z); a2.w = fmaf(wt, e2.w, a2.w);
    }

    __shared__ float sm[4], sl[4];
    __shared__ float sacc[4][512];
    if (lane == 0) { sm[w] = m; sl[w] = l; }
    *(float4*)&sacc[w][lane * 4]       = a1;
    *(float4*)&sacc[w][256 + lane * 4] = a2;
    __syncthreads();

    float M  = fmaxf(fmaxf(sm[0], sm[1]), fmaxf(sm[2], sm[3]));
    float s0 = __expf(sm[0] - M), s1 = __expf(sm[1] - M);
    float s2 = __expf(sm[2] - M), s3 = __expf(sm[3] - M);
    float L  = s0 * sl[0] + s1 * sl[1] + s2 * sl[2] + s3 * sl[3];

    int tid  = threadIdx.x;
    int pidx = b * 32 + tile;
    float acc0 = s0 * sacc[0][tid] + s1 * sacc[1][tid]
               + s2 * sacc[2][tid] + s3 * sacc[3][tid];
    float acc1 = s0 * sacc[0][tid + 256] + s1 * sacc[1][tid + 256]
               + s2 * sacc[2][tid + 256] + s3 * sacc[3][tid + 256];
    if (tid == 0) { pm[pidx] = M; pl[pidx] = L; }
    pacc[(size_t)pidx * HDIM + tid]       = acc0;
    pacc[(size_t)pidx * HDIM + tid + 256] = acc1;
}

// ---------------------------------------------------------------------------
// K5: combine 32 tile-partials per b -> context -> concatH/L[512:1024] bf16
// grid: 64 x 256
// ---------------------------------------------------------------------------
__global__ __launch_bounds__(256) void k_attn_combine(const float* __restrict__ pm,
                                                      const float* __restrict__ pl,
                                                      const float* __restrict__ pacc,
                                                      unsigned short* __restrict__ cH,
                                                      unsigned short* __restrict__ cL) {
    int b   = blockIdx.x;
    int tid = threadIdx.x;
    __shared__ float smv[32], spl[32], ssc[32];
    if (tid < 32) {
        smv[tid] = pm[b * 32 + tid];
        spl[tid] = pl[b * 32 + tid];
    }
    __syncthreads();
    float M = smv[0];
    #pragma unroll
    for (int t = 1; t < 32; t++) M = fmaxf(M, smv[t]);
    if (tid < 32) ssc[tid] = __expf(smv[tid] - M);
    __syncthreads();

    float L = 0.f;
    #pragma unroll
    for (int t = 0; t < 32; t++) L += ssc[t] * spl[t];

    float c0 = 0.f, c1 = 0.f;
    for (int t = 0; t < 32; t++) {
        const float* pa = pacc + (size_t)(b * 32 + t) * HDIM;
        c0 = fmaf(ssc[t], pa[tid],       c0);
        c1 = fmaf(ssc[t], pa[tid + 256], c1);
    }
    float inv = 1.f / L;
    c0 *= inv; c1 *= inv;
    unsigned short h0s, l0s, h1s, l1s;
    split_bf16(c0, h0s, l0s);
    split_bf16(c1, h1s, l1s);
    cH[(size_t)b * 1024 + 512 + tid]       = h0s;
    cL[(size_t)b * 1024 + 512 + tid]       = l0s;
    cH[(size_t)b * 1024 + 512 + tid + 256] = h1s;
    cL[(size_t)b * 1024 + 512 + tid + 256] = l1s;
}

// ---------------------------------------------------------------------------
// K6: classifier via bf16 MFMA, split-float for ~f32 accuracy.
// logits = A@W^T + b;  A = concat (bf16 hi/lo precomputed), W streamed f32
// and split in-reg.  acc += Ah*Wh + Al*Wh + Ah*Wl   (Al*Wl ~2^-16, dropped)
// No LDS: W has zero intra-block reuse; each wave loads its own B-frags
// (4-lane groups tile 128B-contiguous lines). Block: 512 thr = 8 waves,
// tile 64b x 128v (wave = 64b x 16v). grid: 250.
// Epilogue: logits + per-(block,wave,b) partial max/sumexp for log_softmax.
// MFMA frag layout (16x16x32): A lane l: row=l&15, k=(l>>4)*8+i;
// B lane l: col=l&15, k=(l>>4)*8+i; D lane l: row=(l>>4)*4+r, col=l&15.
// ---------------------------------------------------------------------------
__global__ __launch_bounds__(512) void k_classifier(const unsigned short* __restrict__ cH,
                                                    const unsigned short* __restrict__ cL,
                                                    const float* __restrict__ W_cls,
                                                    const float* __restrict__ b_cls,
                                                    float* __restrict__ logits,
                                                    float* __restrict__ pmax,
                                                    float* __restrict__ psum) {
    int t = threadIdx.x;
    int w = t >> 6;            // 0..7
    int l = t & 63;
    int g = l >> 4;            // 0..3  (k-group / D-row group)
    int bl = l & 15;           // A row / D col index
    int v_lane = blockIdx.x * 128 + w * 16 + bl;   // this lane's v column

    const float* pW = W_cls + (size_t)v_lane * 1024 + g * 8;
    const unsigned short* pAh[4];
    const unsigned short* pAl[4];
    #pragma unroll
    for (int bq = 0; bq < 4; bq++) {
        pAh[bq] = cH + (size_t)(bq * 16 + bl) * 1024 + g * 8;
        pAl[bq] = cL + (size_t)(bq * 16 + bl) * 1024 + g * 8;
    }

    f4v acc[4] = {};   // one per bq (16 b-rows each), 16 f32 total

    #pragma unroll 2
    for (int k0 = 0; k0 < 1024; k0 += 32) {
        float4 wf0 = *(const float4*)(pW + k0);
        float4 wf1 = *(const float4*)(pW + k0 + 4);
        float wf[8] = {wf0.x, wf0.y, wf0.z, wf0.w, wf1.x, wf1.y, wf1.z, wf1.w};
        bfrag8 wh, wl;
        #pragma unroll
        for (int q = 0; q < 8; q++) {
            unsigned short hs, ls;
            split_bf16(wf[q], hs, ls);
            wh[q] = (short)hs;
            wl[q] = (short)ls;
        }
        #pragma unroll
        for (int bq = 0; bq < 4; bq++) {
            bfrag8 ah = *(const bfrag8*)(pAh[bq] + k0);
            bfrag8 al = *(const bfrag8*)(pAl[bq] + k0);
            acc[bq] = __builtin_amdgcn_mfma_f32_16x16x32_bf16(ah, wh, acc[bq], 0, 0, 0);
            acc[bq] = __builtin_amdgcn_mfma_f32_16x16x32_bf16(al, wh, acc[bq], 0, 0, 0);
            acc[bq] = __builtin_amdgcn_mfma_f32_16x16x32_bf16(ah, wl, acc[bq], 0, 0, 0);
        }
    }

    float bias = b_cls[v_lane];

    // write logits (D: row = bq*16 + g*4 + r, col = v_lane)
    #pragma unroll
    for (int bq = 0; bq < 4; bq++) {
        #pragma unroll
        for (int r = 0; r < 4; r++) {
            float val = acc[bq][r] + bias;
            int brow = bq * 16 + g * 4 + r;
            logits[(size_t)brow * V_DST + v_lane] = val;
        }
    }
    // per-(block,wave) partial max / sumexp over this wave's 16 v for each b
    size_t pbase = ((size_t)blockIdx.x * 8 + w) * 64;
    #pragma unroll
    for (int bq = 0; bq < 4; bq++) {
        #pragma unroll
        for (int r = 0; r < 4; r++) {
            float val = acc[bq][r] + bias;
            float mv = val;
            mv = fmaxf(mv, __shfl_xor(mv, 1));
            mv = fmaxf(mv, __shfl_xor(mv, 2));
            mv = fmaxf(mv, __shfl_xor(mv, 4));
            mv = fmaxf(mv, __shfl_xor(mv, 8));
            float e = __expf(val - mv);
            e += __shfl_xor(e, 1);
            e += __shfl_xor(e, 2);
            e += __shfl_xor(e, 4);
            e += __shfl_xor(e, 8);
            if (bl == 0) {
                int brow = bq * 16 + g * 4 + r;
                pmax[pbase + brow] = mv;
                psum[pbase + brow] = e;
            }
        }
    }
}

// ---------------------------------------------------------------------------
// K7: combine 2000 partials per b -> lse; subtract in one pass.
// grid: dim3(4,64) x 256 (chunk c covers 8000 floats of the row)
// ---------------------------------------------------------------------------
__global__ __launch_bounds__(256) void k_lsm(const float* __restrict__ pmax,
                                             const float* __restrict__ psum,
                                             float* __restrict__ logits) {
    int c = blockIdx.x;     // 0..3
    int b = blockIdx.y;     // 0..63
    int tid = threadIdx.x;
    int w = tid >> 6, lane = tid & 63;
    __shared__ float sm4[4], sl4[4];

    float m = -INFINITY;
    for (int i = tid; i < 2000; i += 256) m = fmaxf(m, pmax[(size_t)i * 64 + b]);
    #pragma unroll
    for (int off = 32; off; off >>= 1) m = fmaxf(m, __shfl_xor(m, off));
    if (lane == 0) sm4[w] = m;
    __syncthreads();
    float M = fmaxf(fmaxf(sm4[0], sm4[1]), fmaxf(sm4[2], sm4[3]));

    float s = 0.f;
    for (int i = tid; i < 2000; i += 256)
        s += psum[(size_t)i * 64 + b] * __expf(pmax[(size_t)i * 64 + b] - M);
    #pragma unroll
    for (int off = 32; off; off >>= 1) s += __shfl_xor(s, off);
    if (lane == 0) sl4[w] = s;
    __syncthreads();
    float lse = M + logf(sl4[0] + sl4[1] + sl4[2] + sl4[3]);

    float4* row = (float4*)(logits + (size_t)b * V_DST) + c * 2000;
    for (int i = tid; i < 2000; i += 256) {
        float4 v = row[i];
        v.x -= lse; v.y -= lse; v.z -= lse; v.w -= lse;
        row[i] = v;
    }
}

// ---------------------------------------------------------------------------
// launch
// ---------------------------------------------------------------------------
extern "C" void kernel_launch(void* const* d_in, const int* in_sizes, int n_in,
                              void* d_out, int out_size, void* d_ws, size_t ws_size,
                              hipStream_t stream) {
    const int*   dec_inputs = (const int*)  d_in[0];
    const float* enc        = (const float*)d_in[1];
    const float* h0         = (const float*)d_in[2];
    const float* emb        = (const float*)d_in[3];
    const float* W_ih       = (const float*)d_in[4];
    const float* W_hh       = (const float*)d_in[5];
    const float* b_ih       = (const float*)d_in[6];
    const float* b_hh       = (const float*)d_in[7];
    const float* W_attn     = (const float*)d_in[8];
    // d_in[9] = b_attn: constant-per-row shift, cancels in softmax
    const float* W_cls      = (const float*)d_in[10];
    const float* b_cls      = (const float*)d_in[11];

    float* out  = (float*)d_out;            // [64][32000] log-probs
    float* hout = out + (size_t)BB * V_DST; // [64][512] dec_hidden

    // workspace layout (byte offsets)
    char* ws = (char*)d_ws;
    float*          gi     = (float*)(ws + 0);          //  64*1536*4 = 393216
    float*          gh     = (float*)(ws + 393216);     //  393216
    float*          h      = (float*)(ws + 786432);     //  64*512*4  = 131072
    float*          u_part = (float*)(ws + 917504);     //  8*64*512*4 = 1048576
    float*          pm     = (float*)(ws + 1966080);    //  64*32*4   = 8192
    float*          pl     = (float*)(ws + 1974272);    //  8192
    float*          pacc   = (float*)(ws + 1982464);    //  64*32*512*4 = 4194304
    unsigned short* cH     = (unsigned short*)(ws + 6176768);  // 64*1024*2 = 131072
    unsigned short* cL     = (unsigned short*)(ws + 6307840);  // 131072
    float*          pmax   = (float*)(ws + 6438912);    //  2000*64*4 = 512000
    float*          psum   = (float*)(ws + 6950912);    //  512000  (end ~7.46 MB)

    k_gru_gemv    <<<384,          256, 0, stream>>>(dec_inputs, emb, h0, W_ih, W_hh, gi, gh);
    k_gru_gates   <<<64,           128, 0, stream>>>(gi, gh, h0, b_ih, b_hh, h, hout, cH, cL);
    k_u           <<<dim3(8, 64),  256, 0, stream>>>(h, W_attn, u_part);
    k_attn_flash  <<<dim3(32, 64), 256, 0, stream>>>(enc, u_part, pm, pl, pacc);
    k_attn_combine<<<64,           256, 0, stream>>>(pm, pl, pacc, cH, cL);
    k_classifier  <<<250,          512, 0, stream>>>(cH, cL, W_cls, b_cls, out, pmax, psum);
    k_lsm         <<<dim3(4, 64),  256, 0, stream>>>(pmax, psum, out);
}